// Round 1
// baseline (170.433 us; speedup 1.0000x reference)
//
#include <hip/hip_runtime.h>

typedef unsigned short u16;
typedef unsigned int u32;
typedef __bf16 bf16x8 __attribute__((ext_vector_type(8)));
typedef float f32x16 __attribute__((ext_vector_type(16)));

#define C2 (-7.213475204444817f) /* -5/ln2 : exp(-5 t^2) = exp2(C2 t^2) */
#define T1C 0.28650480f          /* e^-1.25 */
#define T2C 0.0067379470f        /* e^-5    */

__device__ __forceinline__ u16 f2bf(float f) {
  u32 u = __float_as_uint(f);
  return (u16)((u + 0x7FFFu + ((u >> 16) & 1u)) >> 16);  // RNE
}

__device__ __forceinline__ f32x16 mfma16(uint4 a, uint4 b, f32x16 c) {
  return __builtin_amdgcn_mfma_f32_32x32x16_bf16(
      __builtin_bit_cast(bf16x8, a), __builtin_bit_cast(bf16x8, b), c, 0, 0, 0);
}

// ---------------------------------------------------------------------------
// Prep (unchanged; validated): f32 weights -> bf16, per-16k-chunk fragment
// order. wst3 granule(c, g) 16 B, g = s*256 + nq*64 + l:
//   content = W_s[k = c*16 + (l>>5)*8 + 0..8)[u = nq*32 + (l&31)]
// ---------------------------------------------------------------------------
__global__ __launch_bounds__(256) void kan_prep(const float* __restrict__ wb,
                                                const float* __restrict__ ws,
                                                u16* __restrict__ wst3) {
  __shared__ u16 tile[6][16][130];
  const int t = threadIdx.x;
  const int c = blockIdx.x;
#pragma unroll
  for (int it = 0; it < 8; ++it) {
    int idx = it * 256 + t;
    int d = idx >> 7, u = idx & 127;
    size_t base = (size_t)(c * 16 + d) * 128 + u;
    const float* p = ws + base * 8;
    float4 v0 = *(const float4*)p;
    float g4 = p[4];
    tile[0][d][u] = f2bf(v0.x);
    tile[1][d][u] = f2bf(v0.y);
    tile[2][d][u] = f2bf(v0.z);
    tile[3][d][u] = f2bf(v0.w);
    tile[4][d][u] = f2bf(g4);
    tile[5][d][u] = f2bf(wb[base]);
  }
  __syncthreads();
#pragma unroll
  for (int i = 0; i < 6; ++i) {
    int g = i * 256 + t;
    int s = g >> 8, r = g & 255;
    int nq = r >> 6, l = r & 63;
    int u = nq * 32 + (l & 31);
    int dbase = (l >> 5) * 8;
    u32 q[4];
#pragma unroll
    for (int j = 0; j < 4; ++j) {
      u32 lo = tile[s][dbase + 2 * j][u];
      u32 hi = tile[s][dbase + 2 * j + 1][u];
      q[j] = lo | (hi << 16);
    }
    uint4 w4; w4.x = q[0]; w4.y = q[1]; w4.z = q[2]; w4.w = q[3];
    *(uint4*)(wst3 + (size_t)c * 12288 + (size_t)g * 8) = w4;
  }
}

// ---------------------------------------------------------------------------
// Main R9: M=32 row tiles, grid 512 -> 2 blocks/CU (16 waves/CU, 4/SIMD).
// LDS: A dbuf 2 x 24 KB = 48 KB/block.  512 thr = 8 waves (kq 0..3 = c16
// within BK=64, wn 0..1 = n-half), wave tile 32m x 64n (acc 4 x f32x16:
// [0,1]=spline nt0/1, [2,3]=base).  16 bodies of BK=64, ONE barrier each.
// Role-stagger: wn=0 waves do rbf->mfma, wn=1 waves mfma->rbf, so each SIMD
// hosts both roles -> VALU and MFMA pipes overlap instead of alternating.
// A slab layout per buffer: s*4096 + p*1024 + kh*512 + slot*16,
//   slot = m ^ (p*2+kh)  (XOR swizzle; reads and writes bank-uniform).
// Writer: thread r=t>>4 (row), o4=t&15 (k-quad): 4 x-values/iter, 8 B
// granule-half per slab.  mfma A[m=lane&31][k=(lane>>5)*8+j]; C/D
// col=lane&31, row=(reg&3)+8*(reg>>2)+4*(lane>>5)  (all validated R2-R8).
// ---------------------------------------------------------------------------
__global__ __launch_bounds__(512, 4) void kan_main(const float* __restrict__ x,
                                                   const u16* __restrict__ wst3,
                                                   float* __restrict__ out) {
  __shared__ __align__(16) char lds[49152];  // 2 x 24576

  const int t = threadIdx.x;
  const int lane = t & 63;
  const int w = t >> 6;
  const int kq = w & 3;   // c16 index within BK=64 body
  const int wn = w >> 2;  // n-half
  const int b0 = blockIdx.x * 32;

  f32x16 acc[4];
#pragma unroll
  for (int i = 0; i < 4; ++i)
#pragma unroll
    for (int j = 0; j < 16; ++j) acc[i][j] = 0.f;

  // ---- rbf writer: thread owns x row r, k-quad o4 of each BK=64 chunk
  const int r = t >> 4, o4 = t & 15;
  const float* xp = x + (size_t)(b0 + r) * 1024 + o4 * 4;
  const u32 aw = ((u32)(o4 >> 2) << 10) + ((u32)((o4 >> 1) & 1) << 9) +
                 ((u32)((r ^ (o4 >> 1)) & 31) << 4) + ((u32)(o4 & 1) << 3);

  // ---- B source (byte): + i*98304 + s*4096 + nt*1024
  const char* bsrc = (const char*)wst3 + kq * 24576 + wn * 2048 + lane * 16;

  // ---- A reader (byte): + s*4096 (+ buf)
  const u32 ar = ((u32)kq << 10) + ((u32)(lane >> 5) << 9) +
                 ((u32)((lane & 31) ^ (kq * 2 + (lane >> 5))) << 4);

  auto rbf_write = [&](char* buf, float4 xv) {
    float xf[4] = {xv.x, xv.y, xv.z, xv.w};
    u32 pk[6][2];
#pragma unroll
    for (int pp = 0; pp < 2; ++pp) {
      u32 lo6[6], hi6[6];
#pragma unroll
      for (int e = 0; e < 2; ++e) {
        float v = xf[2 * pp + e];
        float t0 = C2 * v;
        float P = __builtin_amdgcn_exp2f(t0 * v);  // e^{-5x^2}
        float Qp = __builtin_amdgcn_exp2f(-t0);    // e^{+5x}
        float Qm = __builtin_amdgcn_exp2f(t0);     // e^{-5x}
        float PQ = P * Qp, PQm = P * Qm;
        u32* dst = e ? hi6 : lo6;
        dst[0] = __float_as_uint(PQm * Qm * T2C) + 0x8000u;
        dst[1] = __float_as_uint(PQm * T1C) + 0x8000u;
        dst[2] = __float_as_uint(P) + 0x8000u;
        dst[3] = __float_as_uint(PQ * T1C) + 0x8000u;
        dst[4] = __float_as_uint(PQ * Qp * T2C) + 0x8000u;
        dst[5] = __float_as_uint(v) + 0x8000u;
      }
#pragma unroll
      for (int s = 0; s < 6; ++s)
        pk[s][pp] = __builtin_amdgcn_perm(hi6[s], lo6[s], 0x07060302);
    }
#pragma unroll
    for (int s = 0; s < 6; ++s) {
      uint2 v2; v2.x = pk[s][0]; v2.y = pk[s][1];
      *(uint2*)(buf + s * 4096 + aw) = v2;
    }
  };

  // ---- 6-slab MFMA chain with depth-2 rotating prefetch (short lifetimes)
  auto gemm_chain = [&](const char* cur, const char* bp) {
    uint4 a0 = *(const uint4*)(cur + ar);
    uint4 c0 = *(const uint4*)(bp);
    uint4 c1 = *(const uint4*)(bp + 1024);
    uint4 a1 = *(const uint4*)(cur + 4096 + ar);
    uint4 c2 = *(const uint4*)(bp + 4096);
    uint4 c3 = *(const uint4*)(bp + 4096 + 1024);
#pragma unroll
    for (int s = 0; s < 6; ++s) {
      uint4 au = a0, b0 = c0, b1 = c1;
      a0 = a1; c0 = c2; c1 = c3;
      if (s < 4) {
        a1 = *(const uint4*)(cur + (s + 2) * 4096 + ar);
        c2 = *(const uint4*)(bp + (s + 2) * 4096);
        c3 = *(const uint4*)(bp + (s + 2) * 4096 + 1024);
      }
      if (s < 5) {
        acc[0] = mfma16(au, b0, acc[0]);
        acc[1] = mfma16(au, b1, acc[1]);
      } else {
        acc[2] = mfma16(au, b0, acc[2]);
        acc[3] = mfma16(au, b1, acc[3]);
      }
    }
  };

  // ---- prologue: rbf chunk 0 into buf0; prefetch x for chunk 1
  float4 xc = *(const float4*)xp;
  rbf_write(lds, xc);
  xc = *(const float4*)(xp + 64);
  __syncthreads();

  for (int i = 0; i < 16; ++i) {
    char* cur = lds + (i & 1) * 24576;
    char* nxt = lds + ((i + 1) & 1) * 24576;
    const char* bc = bsrc + (size_t)i * 98304;

    if (wn == 0) {
      // rbf first, then mfma (loads covered by other-role waves)
      if (i < 15) {
        rbf_write(nxt, xc);
        if (i < 14) xc = *(const float4*)(xp + (i + 2) * 64);
      }
      gemm_chain(cur, bc);
    } else {
      // mfma first, then rbf
      gemm_chain(cur, bc);
      if (i < 15) {
        rbf_write(nxt, xc);
        if (i < 14) xc = *(const float4*)(xp + (i + 2) * 64);
      }
    }
    __syncthreads();
  }

  // ---- epilogue: 2 rounds; round q merges (spline q, base 2+q) across
  // kq=1..3 into kq=0, then silu+add+store.  6 slabs x 8 KB = 48 KB.
#pragma unroll
  for (int q = 0; q < 2; ++q) {
    if (kq != 0) {
      char* slab = lds + ((kq - 1) * 2 + wn) * 8192;
#pragma unroll
      for (int rq = 0; rq < 4; ++rq) {
        *(float4*)(slab + rq * 1024 + lane * 16) =
            make_float4(acc[q][4 * rq], acc[q][4 * rq + 1],
                        acc[q][4 * rq + 2], acc[q][4 * rq + 3]);
        *(float4*)(slab + 4096 + rq * 1024 + lane * 16) =
            make_float4(acc[2 + q][4 * rq], acc[2 + q][4 * rq + 1],
                        acc[2 + q][4 * rq + 2], acc[2 + q][4 * rq + 3]);
      }
    }
    __syncthreads();
    if (kq == 0) {
#pragma unroll
      for (int p = 1; p < 4; ++p) {
        const char* slab = lds + ((p - 1) * 2 + wn) * 8192;
#pragma unroll
        for (int rq = 0; rq < 4; ++rq) {
          float4 vs = *(const float4*)(slab + rq * 1024 + lane * 16);
          float4 vb = *(const float4*)(slab + 4096 + rq * 1024 + lane * 16);
          acc[q][4 * rq] += vs.x; acc[q][4 * rq + 1] += vs.y;
          acc[q][4 * rq + 2] += vs.z; acc[q][4 * rq + 3] += vs.w;
          acc[2 + q][4 * rq] += vb.x; acc[2 + q][4 * rq + 1] += vb.y;
          acc[2 + q][4 * rq + 2] += vb.z; acc[2 + q][4 * rq + 3] += vb.w;
        }
      }
      const int col = wn * 64 + q * 32 + (lane & 31);
#pragma unroll
      for (int reg = 0; reg < 16; ++reg) {
        int row = (reg & 3) + 8 * (reg >> 2) + 4 * (lane >> 5);
        float z = acc[2 + q][reg];
        float sv = z / (1.0f + __expf(-z));
        out[(size_t)(b0 + row) * 128 + col] = sv + acc[q][reg];
      }
    }
    __syncthreads();
  }
}

extern "C" void kernel_launch(void* const* d_in, const int* in_sizes, int n_in,
                              void* d_out, int out_size, void* d_ws, size_t ws_size,
                              hipStream_t stream) {
  const float* x  = (const float*)d_in[0];   // [16384][1024] f32
  const float* wb = (const float*)d_in[1];   // [1024][128]   f32
  const float* ws = (const float*)d_in[2];   // [1024][128][8] f32
  u16* wst3 = (u16*)d_ws;                    // [64][1536] granules, 1.5 MB
  float* out = (float*)d_out;                // [16384][128]  f32

  kan_prep<<<dim3(64), 256, 0, stream>>>(wb, ws, wst3);
  kan_main<<<dim3(512), 512, 0, stream>>>(x, wst3, out);
}

// Round 2
// 137.158 us; speedup vs baseline: 1.2426x; 1.2426x over previous
//
#include <hip/hip_runtime.h>

typedef unsigned short u16;
typedef unsigned int u32;
typedef __bf16 bf16x8 __attribute__((ext_vector_type(8)));
typedef float f32x16 __attribute__((ext_vector_type(16)));

#define C2 (-7.213475204444817f) /* -5/ln2 : exp(-5 t^2) = exp2(C2 t^2) */
#define T1C 0.28650480f          /* e^-1.25 */
#define T2C 0.0067379470f        /* e^-5    */

__device__ __forceinline__ u16 f2bf(float f) {
  u32 u = __float_as_uint(f);
  return (u16)((u + 0x7FFFu + ((u >> 16) & 1u)) >> 16);  // RNE
}

__device__ __forceinline__ f32x16 mfma16(uint4 a, uint4 b, f32x16 c) {
  return __builtin_amdgcn_mfma_f32_32x32x16_bf16(
      __builtin_bit_cast(bf16x8, a), __builtin_bit_cast(bf16x8, b), c, 0, 0, 0);
}

// ---------------------------------------------------------------------------
// Prep (unchanged; validated): f32 weights -> bf16, per-16k-chunk fragment
// order. wst3 granule(c, g) 16 B, g = s*256 + nq*64 + l:
//   content = W_s[k = c*16 + (l>>5)*8 + 0..8)[u = nq*32 + (l&31)]
// ---------------------------------------------------------------------------
__global__ __launch_bounds__(256) void kan_prep(const float* __restrict__ wb,
                                                const float* __restrict__ ws,
                                                u16* __restrict__ wst3) {
  __shared__ u16 tile[6][16][130];
  const int t = threadIdx.x;
  const int c = blockIdx.x;
#pragma unroll
  for (int it = 0; it < 8; ++it) {
    int idx = it * 256 + t;
    int d = idx >> 7, u = idx & 127;
    size_t base = (size_t)(c * 16 + d) * 128 + u;
    const float* p = ws + base * 8;
    float4 v0 = *(const float4*)p;
    float g4 = p[4];
    tile[0][d][u] = f2bf(v0.x);
    tile[1][d][u] = f2bf(v0.y);
    tile[2][d][u] = f2bf(v0.z);
    tile[3][d][u] = f2bf(v0.w);
    tile[4][d][u] = f2bf(g4);
    tile[5][d][u] = f2bf(wb[base]);
  }
  __syncthreads();
#pragma unroll
  for (int i = 0; i < 6; ++i) {
    int g = i * 256 + t;
    int s = g >> 8, r = g & 255;
    int nq = r >> 6, l = r & 63;
    int u = nq * 32 + (l & 31);
    int dbase = (l >> 5) * 8;
    u32 q[4];
#pragma unroll
    for (int j = 0; j < 4; ++j) {
      u32 lo = tile[s][dbase + 2 * j][u];
      u32 hi = tile[s][dbase + 2 * j + 1][u];
      q[j] = lo | (hi << 16);
    }
    uint4 w4; w4.x = q[0]; w4.y = q[1]; w4.z = q[2]; w4.w = q[3];
    *(uint4*)(wst3 + (size_t)c * 12288 + (size_t)g * 8) = w4;
  }
}

// ---------------------------------------------------------------------------
// Main R10: in-register rbf (no A-LDS round trip).  256 blocks x 512 thr
// (8 waves: kq 0..3 = K-quarter, wn 0..1 = n-half), wave tile 64m x 64n,
// acc 8 x f32x16 (=[g*2+nt] spline, [4+g*2+nt] base; validated R2-R8).
// LDS holds only raw x tiles: per body (BK=32) 4 kq-windows x [64 rows x
// 32 k] f32 = 32 KB, dbuf 2x32 KB, staged via global_load_lds dwordx4.
// Swizzle: DMA thread t=(row=t>>3, slot q=t&7) SOURCES global quad
// q^(row&7) -> LDS linear; reader XORs the same -> bank-uniform b128 reads.
// Each lane computes its own A-frags: 8 x floats -> 3 exp2 -> 6 slab frags
// (5 rbf + identity), bf16-packed exactly as R8's rbf_write (same absmax).
// B direct from global L2 (fragment-ordered wst3; validated).  8 barriers.
// ---------------------------------------------------------------------------
__global__ __launch_bounds__(512, 2) void kan_main(const float* __restrict__ x,
                                                   const u16* __restrict__ wst3,
                                                   float* __restrict__ out) {
  __shared__ __align__(16) char lds[65536];  // 2 x 32768; epilogue reuses 48 KB

  const int t = threadIdx.x;
  const int lane = t & 63;
  const int w = t >> 6;
  const int kq = w & 3;   // K-quarter (256 k = 16 c16 chunks)
  const int wn = w >> 2;  // n-half
  const int b0 = blockIdx.x * 64;

  f32x16 acc[8];
#pragma unroll
  for (int i = 0; i < 8; ++i)
#pragma unroll
    for (int j = 0; j < 16; ++j) acc[i][j] = 0.f;

  // ---- x DMA: thread t owns (row=t>>3, LDS slot q=t&7); source quad q^(row&7)
  const int srow = t >> 3, sq = t & 7;
  const float* xsrc =
      x + (size_t)(b0 + srow) * 1024 + (size_t)((sq ^ (srow & 7)) * 4);
  // round rr stages window rr (= kq rr): LDS granule rr*512 + t, wave base
  // buf + rr*8192 + w*1024 (wave-uniform; HW adds lane*16).

  auto stage = [&](char* buf, int body) {
    const float* s0 = xsrc + body * 32;
#pragma unroll
    for (int rr = 0; rr < 4; ++rr) {
      __builtin_amdgcn_global_load_lds(
          (const __attribute__((address_space(1))) u32*)(s0 + rr * 256),
          (__attribute__((address_space(3))) u32*)(buf + rr * 8192 + w * 1024),
          16, 0, 0);
    }
  };

  // ---- x reader geometry: window kq, row g*32+(lane&31), quads cc*4+kh*2+{0,1}
  const int rrow = lane & 31;
  const int kh = lane >> 5;
  const int rs = rrow & 7;  // (g*32+rrow)&7 == rrow&7 for both m-subs

  // ---- B source (byte): c16 index = kq*16 + body*2 + cc
  const char* bsrc =
      (const char*)wst3 + (size_t)kq * 393216 + wn * 2048 + lane * 16;

  // ---- 8 x floats -> 6 A-frags (identical math to validated rbf_write)
  auto mkfrag = [&](const float4& xa, const float4& xb, uint4* fr) {
    float xf[8] = {xa.x, xa.y, xa.z, xa.w, xb.x, xb.y, xb.z, xb.w};
    u32 pk[6][4];
#pragma unroll
    for (int pp = 0; pp < 4; ++pp) {
      u32 lo6[6], hi6[6];
#pragma unroll
      for (int e = 0; e < 2; ++e) {
        float xv = xf[2 * pp + e];
        float t0 = C2 * xv;
        float P = __builtin_amdgcn_exp2f(t0 * xv);  // e^{-5x^2}
        float Qp = __builtin_amdgcn_exp2f(-t0);     // e^{+5x}
        float Qm = __builtin_amdgcn_exp2f(t0);      // e^{-5x}
        float PQ = P * Qp, PQm = P * Qm;
        u32* dst = e ? hi6 : lo6;
        dst[0] = __float_as_uint(PQm * Qm * T2C) + 0x8000u;
        dst[1] = __float_as_uint(PQm * T1C) + 0x8000u;
        dst[2] = __float_as_uint(P) + 0x8000u;
        dst[3] = __float_as_uint(PQ * T1C) + 0x8000u;
        dst[4] = __float_as_uint(PQ * Qp * T2C) + 0x8000u;
        dst[5] = __float_as_uint(xv) + 0x8000u;
      }
#pragma unroll
      for (int s = 0; s < 6; ++s)
        pk[s][pp] = __builtin_amdgcn_perm(hi6[s], lo6[s], 0x07060302);
    }
#pragma unroll
    for (int s = 0; s < 6; ++s) {
      fr[s].x = pk[s][0]; fr[s].y = pk[s][1];
      fr[s].z = pk[s][2]; fr[s].w = pk[s][3];
    }
  };

  // ---- prologue
  stage(lds, 0);
  __syncthreads();

  for (int i = 0; i < 8; ++i) {
    char* cur = lds + (i & 1) * 32768;
    char* nxt = lds + ((i + 1) & 1) * 32768;
    if (i < 7) stage(nxt, i + 1);  // DMA overlaps both c16 computes

#pragma unroll
    for (int cc = 0; cc < 2; ++cc) {
      // B fragments for this c16 (L2-resident wst3)
      const char* bc = bsrc + (size_t)(i * 2 + cc) * 24576;
      uint4 b0v[6], b1v[6];
#pragma unroll
      for (int s = 0; s < 6; ++s) {
        b0v[s] = *(const uint4*)(bc + s * 4096);
        b1v[s] = *(const uint4*)(bc + s * 4096 + 1024);
      }
      // x reads (swizzled slots; two b128 per m-sub)
      const char* wbase = cur + kq * 8192;
      const int q0 = cc * 4 + kh * 2;
      const int sA = q0 ^ rs, sB = (q0 + 1) ^ rs;
      const char* r0 = wbase + rrow * 128;
      const char* r1 = wbase + (32 + rrow) * 128;
      float4 xa0 = *(const float4*)(r0 + sA * 16);
      float4 xb0 = *(const float4*)(r0 + sB * 16);
      float4 xa1 = *(const float4*)(r1 + sA * 16);
      float4 xb1 = *(const float4*)(r1 + sB * 16);
      // rbf -> A-frags (VALU covers B/L2 latency)
      uint4 fa[6], fb[6];
      mkfrag(xa0, xb0, fa);
      mkfrag(xa1, xb1, fb);
      // MFMA chain: slabs 0..4 spline, slab 5 base
#pragma unroll
      for (int s = 0; s < 5; ++s) {
        acc[0] = mfma16(fa[s], b0v[s], acc[0]);
        acc[1] = mfma16(fa[s], b1v[s], acc[1]);
        acc[2] = mfma16(fb[s], b0v[s], acc[2]);
        acc[3] = mfma16(fb[s], b1v[s], acc[3]);
      }
      acc[4] = mfma16(fa[5], b0v[5], acc[4]);
      acc[5] = mfma16(fa[5], b1v[5], acc[5]);
      acc[6] = mfma16(fb[5], b0v[5], acc[6]);
      acc[7] = mfma16(fb[5], b1v[5], acc[7]);
    }
    __syncthreads();  // drains DMA (vmcnt) + guards dbuf swap
  }

  // ---- epilogue (validated R8): 4 rounds; round q merges (spline q,
  // base 4+q) across kq=1..3 into kq=0, then silu+add+store.
#pragma unroll
  for (int q = 0; q < 4; ++q) {
    if (kq != 0) {
      char* slab = lds + ((kq - 1) * 2 + wn) * 8192;
#pragma unroll
      for (int rq = 0; rq < 4; ++rq) {
        *(float4*)(slab + rq * 1024 + lane * 16) =
            make_float4(acc[q][4 * rq], acc[q][4 * rq + 1],
                        acc[q][4 * rq + 2], acc[q][4 * rq + 3]);
        *(float4*)(slab + 4096 + rq * 1024 + lane * 16) =
            make_float4(acc[4 + q][4 * rq], acc[4 + q][4 * rq + 1],
                        acc[4 + q][4 * rq + 2], acc[4 + q][4 * rq + 3]);
      }
    }
    __syncthreads();
    if (kq == 0) {
#pragma unroll
      for (int p = 1; p < 4; ++p) {
        const char* slab = lds + ((p - 1) * 2 + wn) * 8192;
#pragma unroll
        for (int rq = 0; rq < 4; ++rq) {
          float4 vs = *(const float4*)(slab + rq * 1024 + lane * 16);
          float4 vb = *(const float4*)(slab + 4096 + rq * 1024 + lane * 16);
          acc[q][4 * rq] += vs.x; acc[q][4 * rq + 1] += vs.y;
          acc[q][4 * rq + 2] += vs.z; acc[q][4 * rq + 3] += vs.w;
          acc[4 + q][4 * rq] += vb.x; acc[4 + q][4 * rq + 1] += vb.y;
          acc[4 + q][4 * rq + 2] += vb.z; acc[4 + q][4 * rq + 3] += vb.w;
        }
      }
      const int col = wn * 64 + (q & 1) * 32 + (lane & 31);
#pragma unroll
      for (int reg = 0; reg < 16; ++reg) {
        int row = (q >> 1) * 32 + (reg & 3) + 8 * (reg >> 2) + 4 * (lane >> 5);
        float z = acc[4 + q][reg];
        float sv = z / (1.0f + __expf(-z));
        out[(size_t)(b0 + row) * 128 + col] = sv + acc[q][reg];
      }
    }
    __syncthreads();
  }
}

extern "C" void kernel_launch(void* const* d_in, const int* in_sizes, int n_in,
                              void* d_out, int out_size, void* d_ws, size_t ws_size,
                              hipStream_t stream) {
  const float* x  = (const float*)d_in[0];   // [16384][1024] f32
  const float* wb = (const float*)d_in[1];   // [1024][128]   f32
  const float* ws = (const float*)d_in[2];   // [1024][128][8] f32
  u16* wst3 = (u16*)d_ws;                    // [64][1536] granules, 1.5 MB
  float* out = (float*)d_out;                // [16384][128]  f32

  kan_prep<<<dim3(64), 256, 0, stream>>>(wb, ws, wst3);
  kan_main<<<dim3(256), 512, 0, stream>>>(x, wst3, out);
}

// Round 3
// 124.246 us; speedup vs baseline: 1.3717x; 1.1039x over previous
//
#include <hip/hip_runtime.h>

typedef unsigned short u16;
typedef unsigned int u32;
typedef __bf16 bf16x8 __attribute__((ext_vector_type(8)));
typedef float f32x16 __attribute__((ext_vector_type(16)));

#define C2 (-7.213475204444817f) /* -5/ln2 : exp(-5 t^2) = exp2(C2 t^2) */
#define T1C 0.28650480f          /* e^-1.25 */
#define T2C 0.0067379470f        /* e^-5    */

__device__ __forceinline__ u16 f2bf(float f) {
  u32 u = __float_as_uint(f);
  return (u16)((u + 0x7FFFu + ((u >> 16) & 1u)) >> 16);  // RNE
}

__device__ __forceinline__ f32x16 mfma16(uint4 a, uint4 b, f32x16 c) {
  return __builtin_amdgcn_mfma_f32_32x32x16_bf16(
      __builtin_bit_cast(bf16x8, a), __builtin_bit_cast(bf16x8, b), c, 0, 0, 0);
}

// ---------------------------------------------------------------------------
// Prep (unchanged; validated): f32 weights -> bf16, per-16k-chunk fragment
// order. wst3 granule(c, g) 16 B, g = s*256 + nq*64 + l:
//   content = W_s[k = c*16 + (l>>5)*8 + 0..8)[u = nq*32 + (l&31)]
// ---------------------------------------------------------------------------
__global__ __launch_bounds__(256) void kan_prep(const float* __restrict__ wb,
                                                const float* __restrict__ ws,
                                                u16* __restrict__ wst3) {
  __shared__ u16 tile[6][16][130];
  const int t = threadIdx.x;
  const int c = blockIdx.x;
#pragma unroll
  for (int it = 0; it < 8; ++it) {
    int idx = it * 256 + t;
    int d = idx >> 7, u = idx & 127;
    size_t base = (size_t)(c * 16 + d) * 128 + u;
    const float* p = ws + base * 8;
    float4 v0 = *(const float4*)p;
    float g4 = p[4];
    tile[0][d][u] = f2bf(v0.x);
    tile[1][d][u] = f2bf(v0.y);
    tile[2][d][u] = f2bf(v0.z);
    tile[3][d][u] = f2bf(v0.w);
    tile[4][d][u] = f2bf(g4);
    tile[5][d][u] = f2bf(wb[base]);
  }
  __syncthreads();
#pragma unroll
  for (int i = 0; i < 6; ++i) {
    int g = i * 256 + t;
    int s = g >> 8, r = g & 255;
    int nq = r >> 6, l = r & 63;
    int u = nq * 32 + (l & 31);
    int dbase = (l >> 5) * 8;
    u32 q[4];
#pragma unroll
    for (int j = 0; j < 4; ++j) {
      u32 lo = tile[s][dbase + 2 * j][u];
      u32 hi = tile[s][dbase + 2 * j + 1][u];
      q[j] = lo | (hi << 16);
    }
    uint4 w4; w4.x = q[0]; w4.y = q[1]; w4.z = q[2]; w4.w = q[3];
    *(uint4*)(wst3 + (size_t)c * 12288 + (size_t)g * 8) = w4;
  }
}

// ---------------------------------------------------------------------------
// Main R11: producer/consumer wave specialization.  256 blocks x 512 thr.
// Waves 0..3 = PRODUCERS: rbf -> LDS slabs (R8 layout verbatim), each lane
// owns rows r0 and r0+32 at k-octet o; rbf computed ONCE per block.
// Waves 4..7 = CONSUMERS (one per SIMD under i%4 wave->SIMD): wn = n-quad
// (32 cols), full 64 rows, FULL K accumulate (no k-partial merge epilogue).
// acc[0,1]=spline g0/g1, acc[2,3]=base g0/g1 (64 AGPR).  B direct from L2
// (fragment-ordered wst3, 24 coalesced dwordx4 issued at slot top), A from
// LDS slabs, 48 MFMA/slot wrapped in s_setprio(1) (role diversity -> T5).
// LDS: body slabs dbuf 2 x 48 KB; 16 slots, one barrier each (+1 prologue;
// both roles execute identical barrier counts -> wave-level s_barrier ok).
// A granule-set (s, g, p): byte = s*8192 + (g*4+p)*1024 + kh*512 + slot*16,
// slot = (m ^ (p*2+kh)) & 31 (XOR swizzle; writer (r,o) -> slot r^o at
// half o&1; o = p*2+kh).  mfma A[m=lane&31][k=(lane>>5)*8+j]; C/D
// col=lane&31, row=(reg&3)+8*(reg>>2)+4*(lane>>5)   (validated R2-R10).
// ---------------------------------------------------------------------------
__global__ __launch_bounds__(512, 2) void kan_main(const float* __restrict__ x,
                                                   const u16* __restrict__ wst3,
                                                   float* __restrict__ out) {
  __shared__ __align__(16) char lds[98304];  // 2 x 49152

  const int t = threadIdx.x;
  const int lane = t & 63;
  const int w = t >> 6;
  const int b0 = blockIdx.x * 64;

  if (w < 4) {
    // ================= PRODUCERS =================
    const int pid = (w << 6) + lane;  // 0..255
    const int r0 = pid >> 3;          // 0..31
    const int o = pid & 7;            // k-octet within BK=64 body
    const u32 aw0 = ((u32)(o >> 1) << 10) + ((u32)(o & 1) << 9) +
                    ((u32)((r0 ^ o) & 31) << 4);
    const u32 aw1 = aw0 + 4096;  // g=1 (rows 32..63)
    const float* xpA = x + (size_t)(b0 + r0) * 1024 + o * 8;
    const float* xpB = xpA + 32 * 1024;

    auto rbf6 = [&](char* buf, u32 aw, float4 xa, float4 xb) {
      float xf[8] = {xa.x, xa.y, xa.z, xa.w, xb.x, xb.y, xb.z, xb.w};
      u32 pk[6][4];
#pragma unroll
      for (int pp = 0; pp < 4; ++pp) {
        u32 lo6[6], hi6[6];
#pragma unroll
        for (int e = 0; e < 2; ++e) {
          float xv = xf[2 * pp + e];
          float t0 = C2 * xv;
          float P = __builtin_amdgcn_exp2f(t0 * xv);  // e^{-5x^2}
          float Qp = __builtin_amdgcn_exp2f(-t0);     // e^{+5x}
          float Qm = __builtin_amdgcn_exp2f(t0);      // e^{-5x}
          float PQ = P * Qp, PQm = P * Qm;
          u32* dst = e ? hi6 : lo6;
          dst[0] = __float_as_uint(PQm * Qm * T2C) + 0x8000u;
          dst[1] = __float_as_uint(PQm * T1C) + 0x8000u;
          dst[2] = __float_as_uint(P) + 0x8000u;
          dst[3] = __float_as_uint(PQ * T1C) + 0x8000u;
          dst[4] = __float_as_uint(PQ * Qp * T2C) + 0x8000u;
          dst[5] = __float_as_uint(xv) + 0x8000u;
        }
#pragma unroll
        for (int s = 0; s < 6; ++s)
          pk[s][pp] = __builtin_amdgcn_perm(hi6[s], lo6[s], 0x07060302);
      }
#pragma unroll
      for (int s = 0; s < 6; ++s) {
        uint4 v; v.x = pk[s][0]; v.y = pk[s][1]; v.z = pk[s][2]; v.w = pk[s][3];
        *(uint4*)(buf + s * 8192 + aw) = v;
      }
    };

    // prologue: body 0 -> buf0; then load x for body 1
    float4 xA0 = *(const float4*)(xpA);
    float4 xA1 = *(const float4*)(xpA + 4);
    float4 xB0 = *(const float4*)(xpB);
    float4 xB1 = *(const float4*)(xpB + 4);
    rbf6(lds, aw0, xA0, xA1);
    rbf6(lds, aw1, xB0, xB1);
    xA0 = *(const float4*)(xpA + 64);
    xA1 = *(const float4*)(xpA + 68);
    xB0 = *(const float4*)(xpB + 64);
    xB1 = *(const float4*)(xpB + 68);
    __syncthreads();

    for (int i = 0; i < 16; ++i) {
      if (i < 15) {
        char* nxt = lds + ((i + 1) & 1) * 49152;
        rbf6(nxt, aw0, xA0, xA1);
        rbf6(nxt, aw1, xB0, xB1);
        if (i < 14) {  // issue after last use of regs; lands before next slot
          xA0 = *(const float4*)(xpA + (i + 2) * 64);
          xA1 = *(const float4*)(xpA + (i + 2) * 64 + 4);
          xB0 = *(const float4*)(xpB + (i + 2) * 64);
          xB1 = *(const float4*)(xpB + (i + 2) * 64 + 4);
        }
      }
      __syncthreads();
    }
    // producers exit; no epilogue
  } else {
    // ================= CONSUMERS =================
    const int wn = w - 4;        // n-quad: cols wn*32 .. wn*32+31
    const int kh = lane >> 5;
    u32 aoff[4];
#pragma unroll
    for (int p = 0; p < 4; ++p)
      aoff[p] = (u32)(p * 1024 + kh * 512 +
                      ((((lane & 31) ^ (p * 2 + kh)) & 31) << 4));
    const char* bb = (const char*)wst3 + wn * 1024 + lane * 16;

    f32x16 acc[4];
#pragma unroll
    for (int i = 0; i < 4; ++i)
#pragma unroll
      for (int j = 0; j < 16; ++j) acc[i][j] = 0.f;

    __syncthreads();  // matches producer prologue barrier

    for (int i = 0; i < 16; ++i) {
      const char* cur = lds + (i & 1) * 49152;
      // issue all B loads for this body up front (coalesced, L2-resident)
      uint4 bv[4][6];
#pragma unroll
      for (int p = 0; p < 4; ++p)
#pragma unroll
        for (int s = 0; s < 6; ++s)
          bv[p][s] =
              *(const uint4*)(bb + (size_t)(i * 4 + p) * 24576 + s * 4096);
#pragma unroll
      for (int p = 0; p < 4; ++p) {
        uint4 a0[6], a1[6];
#pragma unroll
        for (int s = 0; s < 6; ++s) {
          a0[s] = *(const uint4*)(cur + s * 8192 + aoff[p]);
          a1[s] = *(const uint4*)(cur + s * 8192 + 4096 + aoff[p]);
        }
        __builtin_amdgcn_s_setprio(1);
#pragma unroll
        for (int s = 0; s < 5; ++s) {
          acc[0] = mfma16(a0[s], bv[p][s], acc[0]);
          acc[1] = mfma16(a1[s], bv[p][s], acc[1]);
        }
        acc[2] = mfma16(a0[5], bv[p][5], acc[2]);
        acc[3] = mfma16(a1[5], bv[p][5], acc[3]);
        __builtin_amdgcn_s_setprio(0);
      }
      __syncthreads();
    }

    // epilogue: direct silu+add+store (full-K acc; no merge)
    const int col = wn * 32 + (lane & 31);
#pragma unroll
    for (int g = 0; g < 2; ++g) {
#pragma unroll
      for (int reg = 0; reg < 16; ++reg) {
        int row = g * 32 + (reg & 3) + 8 * (reg >> 2) + 4 * (lane >> 5);
        float z = acc[2 + g][reg];
        float sv = z / (1.0f + __expf(-z));
        out[(size_t)(b0 + row) * 128 + col] = sv + acc[g][reg];
      }
    }
  }
}

extern "C" void kernel_launch(void* const* d_in, const int* in_sizes, int n_in,
                              void* d_out, int out_size, void* d_ws, size_t ws_size,
                              hipStream_t stream) {
  const float* x  = (const float*)d_in[0];   // [16384][1024] f32
  const float* wb = (const float*)d_in[1];   // [1024][128]   f32
  const float* ws = (const float*)d_in[2];   // [1024][128][8] f32
  u16* wst3 = (u16*)d_ws;                    // [64][1536] granules, 1.5 MB
  float* out = (float*)d_out;                // [16384][128]  f32

  kan_prep<<<dim3(64), 256, 0, stream>>>(wb, ws, wst3);
  kan_main<<<dim3(256), 512, 0, stream>>>(x, wst3, out);
}